// Round 6
// baseline (209.983 us; speedup 1.0000x reference)
//
#include <hip/hip_runtime.h>
#include <stdint.h>

// Round 6: attn restructured for step-efficiency + sustained 16 waves/CU.
//  - QBLK=32, KVBLK=128, 8-wave (512thr) blocks, 2 blocks/CU (launch_bounds(512,4)).
//  - Wave w: QK^T kv-strip w*16 (K direct L2->reg, zero dup); PV d-slice w*64
//    (V direct L2->reg, zero dup). L2 traffic = 64B/score-position (minimal).
//  - Q staged ONCE in LDS (32KB, XOR-swizzled via pre-swizzled gload_lds source).
//  - Ps double-buffered (2x8KB) -> ONE lgkm-only barrier per kv-step.
//  - Co-resident pair (rank, rank+32) -> tiles (t, 63-t): equal per-CU totals.
// K1/K2 unchanged (proven).

typedef __attribute__((ext_vector_type(4))) float f32x4;
typedef __attribute__((ext_vector_type(8))) short short8;
typedef __attribute__((ext_vector_type(4))) short short4b;

__device__ __forceinline__ short f2bf(float f) {
    union { float f; uint32_t u; } v; v.f = f;
    uint32_t r = (v.u + 0x7FFFu + ((v.u >> 16) & 1u)) >> 16;   // RNE
    return (short)r;
}
__device__ __forceinline__ float bf2f(short s) {
    union { uint32_t u; float f; } v; v.u = ((uint32_t)(uint16_t)s) << 16; return v.f;
}
__device__ __forceinline__ float sigm(float x) { return 1.0f / (1.0f + __expf(-x)); }

__device__ __forceinline__ void gload_lds16(const void* g, void* l) {
    __builtin_amdgcn_global_load_lds(
        (const __attribute__((address_space(1))) void*)g,
        (__attribute__((address_space(3))) void*)l, 16, 0, 0);
}

// barrier WITHOUT vmcnt drain (LDS visibility only)
#define BARL() asm volatile("s_waitcnt lgkmcnt(0)\n\ts_barrier" ::: "memory")

// ---------------------------------------------------------------- K1: weights
__global__ __launch_bounds__(256) void prep_weights(
    const float* __restrict__ Wq, const float* __restrict__ Wv, const float* __restrict__ Wk,
    short* __restrict__ Wt)
{
    __shared__ float T[64 * 68];
    int bid = blockIdx.x;
    int w = bid >> 6;                 // 0..2
    int tile = bid & 63;
    int n0 = (tile & 7) * 64;
    int k0 = (tile >> 3) * 64;
    const float* W = (w == 0) ? Wq : (w == 1) ? Wv : Wk;
    int t = threadIdx.x;
    int tr = t >> 4, tc = t & 15;
    for (int rr = 0; rr < 4; ++rr) {
        int row = rr * 16 + tr;       // k-local
        float4 v = *reinterpret_cast<const float4*>(&W[(size_t)(k0 + row) * 512 + n0 + tc * 4]);
        T[row * 68 + tc * 4 + 0] = v.x;
        T[row * 68 + tc * 4 + 1] = v.y;
        T[row * 68 + tc * 4 + 2] = v.z;
        T[row * 68 + tc * 4 + 3] = v.w;
    }
    __syncthreads();
    for (int wr = 0; wr < 4; ++wr) {
        int nl = wr * 16 + tr;        // n-local
        short4b o;
        for (int i = 0; i < 4; ++i) o[i] = f2bf(T[(tc * 4 + i) * 68 + nl]);
        *reinterpret_cast<short4b*>(&Wt[((size_t)(w * 512 + n0 + nl)) * 512 + k0 + tc * 4]) = o;
    }
}

// ---------------------------------------------------------------- K2: QKV GEMM
__global__ __launch_bounds__(256) void qkv_gemm(
    const float* __restrict__ X,     // [16384][512] fp32
    const short* __restrict__ Wt,    // [3][512 n][512 k] bf16
    short* __restrict__ Qb, short* __restrict__ Kb, short* __restrict__ VtG)
{
    __shared__ short SMEM[128 * 128];
    short* As = SMEM;
    short* Bs = SMEM + 128 * 64;

    int bx = blockIdx.x;
    int mt = bx & 127;
    int y = bx >> 7;
    int w = y >> 2, nt = y & 3;
    int m0 = mt * 128, n0 = nt * 128;

    int tid = threadIdx.x;
    int wid = tid >> 6, lane = tid & 63;
    int wr = wid >> 1, wc = wid & 1;
    int ln = lane & 15, hi = lane >> 4;

    f32x4 acc[4][4];
    for (int i = 0; i < 4; ++i) for (int j = 0; j < 4; ++j) acc[i][j] = {0.f, 0.f, 0.f, 0.f};

    const short* WtW = Wt + (size_t)w * 512 * 512;

    for (int ko = 0; ko < 8; ++ko) {
        int k0 = ko * 64;
        __syncthreads();
        for (int j = 0; j < 8; ++j) {
            int c = j * 256 + tid;
            int row = c >> 4, col4 = c & 15;
            float4 v = *reinterpret_cast<const float4*>(&X[(size_t)(m0 + row) * 512 + k0 + col4 * 4]);
            short4b s;
            s[0] = f2bf(v.x); s[1] = f2bf(v.y); s[2] = f2bf(v.z); s[3] = f2bf(v.w);
            *reinterpret_cast<short4b*>(&As[row * 64 + ((col4 * 4) ^ ((row & 7) << 3))]) = s;
        }
        for (int j = 0; j < 4; ++j) {
            int c = j * 256 + tid;
            int row = c >> 3, col8 = c & 7;
            short8 v = *reinterpret_cast<const short8*>(&WtW[(size_t)(n0 + row) * 512 + k0 + col8 * 8]);
            *reinterpret_cast<short8*>(&Bs[row * 64 + ((col8 * 8) ^ ((row & 7) << 3))]) = v;
        }
        __syncthreads();
        for (int kk = 0; kk < 2; ++kk) {
            int kof = kk * 32 + hi * 8;
            int sw = (ln & 7) << 3;
            short8 af[4], bf[4];
            for (int mf = 0; mf < 4; ++mf)
                af[mf] = *reinterpret_cast<const short8*>(&As[(wr * 64 + mf * 16 + ln) * 64 + (kof ^ sw)]);
            for (int nf = 0; nf < 4; ++nf)
                bf[nf] = *reinterpret_cast<const short8*>(&Bs[(wc * 64 + nf * 16 + ln) * 64 + (kof ^ sw)]);
            for (int mf = 0; mf < 4; ++mf)
                for (int nf = 0; nf < 4; ++nf)
                    acc[mf][nf] = __builtin_amdgcn_mfma_f32_16x16x32_bf16(af[mf], bf[nf], acc[mf][nf], 0, 0, 0);
        }
    }
    __syncthreads();

    if (w < 2) {
        short* O = (w == 0) ? Qb : Kb;
        for (int mf = 0; mf < 4; ++mf)
            for (int nf = 0; nf < 4; ++nf)
                for (int j = 0; j < 4; ++j) {
                    int row = m0 + wr * 64 + mf * 16 + hi * 4 + j;
                    int col = n0 + wc * 64 + nf * 16 + ln;
                    O[(size_t)row * 512 + col] = f2bf(sigm(acc[mf][nf][j]));
                }
    } else {
        for (int mf = 0; mf < 4; ++mf)
            for (int nf = 0; nf < 4; ++nf)
                for (int j = 0; j < 4; ++j) {
                    int ml = wr * 64 + mf * 16 + hi * 4 + j;       // s-local
                    int nl = wc * 64 + nf * 16 + ln;               // d-local
                    SMEM[nl * 128 + (ml ^ ((nl & 7) << 3))] = f2bf(sigm(acc[mf][nf][j]));
                }
        __syncthreads();
        int bb = m0 >> 11;
        int s0 = m0 & 2047;
        int d = tid >> 1, h = tid & 1;
        for (int i = 0; i < 8; ++i) {
            int s8 = h * 64 + i * 8;
            short8 v = *reinterpret_cast<const short8*>(&SMEM[d * 128 + (s8 ^ ((d & 7) << 3))]);
            *reinterpret_cast<short8*>(&VtG[((size_t)(bb * 512 + n0 + d)) * 2048 + s0 + s8]) = v;
        }
    }
}

// ---------------------------------------------------------------- K3: attention
// 512 blocks x 512 thr (8 waves). b=bid&7 (XCD), rank=bid>>3; t = rank<32 ? rank : 95-rank
// (co-resident pair (rank, rank+32) -> tiles (t, 63-t): equal per-CU totals).
// QBLK=32, KVBLK=128. Wave w: QK^T kv-strip w*16 (K direct from L2);
// PV d-slice w*64 (V direct from L2). Q in LDS (swizzled); Ps dbuf; 1 barrier/step.
__global__ __launch_bounds__(512, 4) void attn_kernel(
    const short* __restrict__ Qb, const short* __restrict__ Kb, const short* __restrict__ VtG,
    float* __restrict__ Out)
{
    __shared__ short Qs[32 * 512];     // [q][k] shorts; col c at (c ^ ((r&7)<<3))
    __shared__ short Ps[2][32 * 128];  // [q][kv] shorts; col c at (c ^ ((r&7)<<3))
    __shared__ float lsum[8][32];      // per-wave kv-strip partial denominators

    const float scale = 0.044194173824159216f;   // 1/sqrt(512)

    int bid = blockIdx.x;
    int b = bid & 7;
    int rank = bid >> 3;
    int t = (rank < 32) ? rank : 95 - rank;
    int q0 = t * 32;
    int nsteps = ((q0 + 30) >> 7) + 1;           // kv-tiles of 128 covering j < q0+31

    int tid = threadIdx.x;
    int w = tid >> 6, lane = tid & 63;
    int ln = lane & 15, hi = lane >> 4;

    const short* Kbb = Kb + (size_t)b * 2048 * 512;
    const short* Vbb = VtG + (size_t)b * 512 * 2048;

    // ---- stage Q[32][512] into LDS once (pre-swizzled source, linear dest)
    {
        const short* Qsrc = Qb + (size_t)b * 2048 * 512 + (size_t)q0 * 512;
#pragma unroll
        for (int j = 0; j < 4; ++j) {
            int r = w * 4 + j;
            const short* src = Qsrc + (size_t)r * 512 + ((lane * 8) ^ ((r & 7) << 3));
            gload_lds16(src, &Qs[r * 512]);
        }
    }
    asm volatile("s_waitcnt vmcnt(0) lgkmcnt(0)\n\ts_barrier" ::: "memory");

    f32x4 acco[2][4];                  // [rf][cf]: rows rf*16+, cols w*64+cf*16+
#pragma unroll
    for (int i = 0; i < 2; ++i)
#pragma unroll
        for (int j = 0; j < 4; ++j) acco[i][j] = {0.f, 0.f, 0.f, 0.f};
    float dsum[2][4] = {{0.f, 0.f, 0.f, 0.f}, {0.f, 0.f, 0.f, 0.f}};

    // per-wave base pointers
    const short* Kw = Kbb + (size_t)(w * 16 + ln) * 512 + hi * 8;   // + kv0*512 + ks*32
    const short* Vw = Vbb + (size_t)(w * 64 + ln) * 2048 + hi * 8;  // + cf*16*2048 + kv0 + kst*32

    int cur = 0;
    for (int kt = 0; kt < nsteps; ++kt) {
        int kv0 = kt * 128;

        // ---- QK^T: S[32][strip w*16], full K=512; K streamed from L2 in 2 halves
        f32x4 s0 = {0.f, 0.f, 0.f, 0.f}, s1 = {0.f, 0.f, 0.f, 0.f};
        int qsw = (ln & 7) << 3;
#pragma unroll
        for (int half = 0; half < 2; ++half) {
            short8 kf[8];
#pragma unroll
            for (int k8 = 0; k8 < 8; ++k8)
                kf[k8] = *reinterpret_cast<const short8*>(Kw + (size_t)kv0 * 512 + (half * 8 + k8) * 32);
            __builtin_amdgcn_s_setprio(1);
#pragma unroll
            for (int k8 = 0; k8 < 8; ++k8) {
                int c = (half * 8 + k8) * 32 + hi * 8;
                short8 qa = *reinterpret_cast<const short8*>(&Qs[(size_t)ln * 512 + (c ^ qsw)]);
                short8 qb2 = *reinterpret_cast<const short8*>(&Qs[(size_t)(16 + ln) * 512 + (c ^ qsw)]);
                s0 = __builtin_amdgcn_mfma_f32_16x16x32_bf16(qa, kf[k8], s0, 0, 0, 0);
                s1 = __builtin_amdgcn_mfma_f32_16x16x32_bf16(qb2, kf[k8], s1, 0, 0, 0);
            }
            __builtin_amdgcn_s_setprio(0);
        }

        // ---- softmax: strict mask j<i, exp, Ps (bf16, swizzled), in-reg denom
        {
            int jcol = kv0 + w * 16 + ln;
            int pc = (w * 16 + ln);
#pragma unroll
            for (int rf = 0; rf < 2; ++rf) {
                const f32x4& sa = rf ? s1 : s0;
#pragma unroll
                for (int j = 0; j < 4; ++j) {
                    int rl = rf * 16 + hi * 4 + j;
                    int irow = q0 + rl;
                    float p = (jcol < irow) ? __expf(sa[j] * scale) : 0.f;
                    short hs = f2bf(p);
                    Ps[cur][rl * 128 + (pc ^ ((rl & 7) << 3))] = hs;
                    dsum[rf][j] += bf2f(hs);
                }
            }
        }
        BARL();                                   // Ps[cur] visible block-wide

        // ---- PV: O[32][w*64..+64] += P[32][128] * V[128][slice]
#pragma unroll
        for (int kst = 0; kst < 4; ++kst) {
            short8 vb[4];
#pragma unroll
            for (int cf = 0; cf < 4; ++cf)
                vb[cf] = *reinterpret_cast<const short8*>(
                    Vw + (size_t)(cf * 16) * 2048 + kv0 + kst * 32);
            int pcc = kst * 32 + hi * 8;
            short8 pa0 = *reinterpret_cast<const short8*>(
                &Ps[cur][(size_t)ln * 128 + (pcc ^ ((ln & 7) << 3))]);
            short8 pa1 = *reinterpret_cast<const short8*>(
                &Ps[cur][(size_t)(16 + ln) * 128 + (pcc ^ ((ln & 7) << 3))]);
            __builtin_amdgcn_s_setprio(1);
#pragma unroll
            for (int cf = 0; cf < 4; ++cf) {
                acco[0][cf] = __builtin_amdgcn_mfma_f32_16x16x32_bf16(pa0, vb[cf], acco[0][cf], 0, 0, 0);
                acco[1][cf] = __builtin_amdgcn_mfma_f32_16x16x32_bf16(pa1, vb[cf], acco[1][cf], 0, 0, 0);
            }
            __builtin_amdgcn_s_setprio(0);
        }
        cur ^= 1;                                 // next step writes other Ps frame
    }

    // ---- denominators: reduce per-wave strip sums over 16 lanes, combine across waves
#pragma unroll
    for (int rf = 0; rf < 2; ++rf)
#pragma unroll
        for (int j = 0; j < 4; ++j) {
            float s = dsum[rf][j];
            s += __shfl_xor(s, 1);
            s += __shfl_xor(s, 2);
            s += __shfl_xor(s, 4);
            s += __shfl_xor(s, 8);
            if (ln == 0) lsum[w][rf * 16 + hi * 4 + j] = s;
        }
    __syncthreads();

    // ---- normalize + store (row 0 of each batch -> zeros)
#pragma unroll
    for (int rf = 0; rf < 2; ++rf)
#pragma unroll
        for (int j = 0; j < 4; ++j) {
            int rl = rf * 16 + hi * 4 + j;
            int i = q0 + rl;
            float denom = 0.f;
#pragma unroll
            for (int ww = 0; ww < 8; ++ww) denom += lsum[ww][rl];
            float rd = (i == 0) ? 0.f : 1.0f / denom;
            float* orow = Out + ((size_t)b * 2048 + i) * 512 + w * 64 + ln;
#pragma unroll
            for (int cf = 0; cf < 4; ++cf)
                orow[cf * 16] = acco[rf][cf][j] * rd;
        }
}

// ---------------------------------------------------------------- launch
extern "C" void kernel_launch(void* const* d_in, const int* in_sizes, int n_in,
                              void* d_out, int out_size, void* d_ws, size_t ws_size,
                              hipStream_t stream) {
    const float* X  = (const float*)d_in[0];
    const float* Wq = (const float*)d_in[1];
    const float* Wv = (const float*)d_in[2];
    const float* Wk = (const float*)d_in[3];
    float* Out = (float*)d_out;

    char* ws = (char*)d_ws;
    const size_t WT_BYTES = (size_t)3 * 512 * 512 * 2;        // 1.5 MB
    const size_t MAT_BYTES = (size_t)16384 * 512 * 2;         // 16 MB each
    short* Wt = (short*)ws;
    short* Qb = (short*)(ws + WT_BYTES);
    short* Kb = (short*)(ws + WT_BYTES + MAT_BYTES);
    short* Vt = (short*)(ws + WT_BYTES + 2 * MAT_BYTES);

    prep_weights<<<192, 256, 0, stream>>>(Wq, Wv, Wk, Wt);
    qkv_gemm<<<1536, 256, 0, stream>>>(X, Wt, Qb, Kb, Vt);
    attn_kernel<<<512, 512, 0, stream>>>(Qb, Kb, Vt, Out);
}

// Round 7
// 141.952 us; speedup vs baseline: 1.4792x; 1.4792x over previous
//
#include <hip/hip_runtime.h>
#include <stdint.h>

// Round 7: attention factorized into two causal GEMM passes (m97-structure clones).
//  PA score_pass: P = exp(mask(Q K^T scale)) per causal 128^2 tile -> compact bf16 in ws,
//                 + per-tile row sums Dpart (deterministic, no atomics).
//  PB pv_pass:    O = (P V) / denom, K-loop over causal tiles; denom reduced in prologue.
//  Rationale: R2-R6 flash-style loops all cost ~2.2us/32-row step (m233 2-phase stall);
//  the K2/m97 GEMM structure empirically amortizes to ~0.8us/kstep at 4 blocks/CU.
// K1/K2 unchanged (proven).

typedef __attribute__((ext_vector_type(4))) float f32x4;
typedef __attribute__((ext_vector_type(8))) short short8;
typedef __attribute__((ext_vector_type(4))) short short4b;

__device__ __forceinline__ short f2bf(float f) {
    union { float f; uint32_t u; } v; v.f = f;
    uint32_t r = (v.u + 0x7FFFu + ((v.u >> 16) & 1u)) >> 16;   // RNE
    return (short)r;
}
__device__ __forceinline__ float bf2f(short s) {
    union { uint32_t u; float f; } v; v.u = ((uint32_t)(uint16_t)s) << 16; return v.f;
}
__device__ __forceinline__ float sigm(float x) { return 1.0f / (1.0f + __expf(-x)); }

__device__ __forceinline__ void gload_lds16(const void* g, void* l) {
    __builtin_amdgcn_global_load_lds(
        (const __attribute__((address_space(1))) void*)g,
        (__attribute__((address_space(3))) void*)l, 16, 0, 0);
}

// ---------------------------------------------------------------- K1: weights
__global__ __launch_bounds__(256) void prep_weights(
    const float* __restrict__ Wq, const float* __restrict__ Wv, const float* __restrict__ Wk,
    short* __restrict__ Wt)
{
    __shared__ float T[64 * 68];
    int bid = blockIdx.x;
    int w = bid >> 6;                 // 0..2
    int tile = bid & 63;
    int n0 = (tile & 7) * 64;
    int k0 = (tile >> 3) * 64;
    const float* W = (w == 0) ? Wq : (w == 1) ? Wv : Wk;
    int t = threadIdx.x;
    int tr = t >> 4, tc = t & 15;
    for (int rr = 0; rr < 4; ++rr) {
        int row = rr * 16 + tr;       // k-local
        float4 v = *reinterpret_cast<const float4*>(&W[(size_t)(k0 + row) * 512 + n0 + tc * 4]);
        T[row * 68 + tc * 4 + 0] = v.x;
        T[row * 68 + tc * 4 + 1] = v.y;
        T[row * 68 + tc * 4 + 2] = v.z;
        T[row * 68 + tc * 4 + 3] = v.w;
    }
    __syncthreads();
    for (int wr = 0; wr < 4; ++wr) {
        int nl = wr * 16 + tr;        // n-local
        short4b o;
        for (int i = 0; i < 4; ++i) o[i] = f2bf(T[(tc * 4 + i) * 68 + nl]);
        *reinterpret_cast<short4b*>(&Wt[((size_t)(w * 512 + n0 + nl)) * 512 + k0 + tc * 4]) = o;
    }
}

// ---------------------------------------------------------------- K2: QKV GEMM
__global__ __launch_bounds__(256) void qkv_gemm(
    const float* __restrict__ X,     // [16384][512] fp32
    const short* __restrict__ Wt,    // [3][512 n][512 k] bf16
    short* __restrict__ Qb, short* __restrict__ Kb, short* __restrict__ VtG)
{
    __shared__ short SMEM[128 * 128];
    short* As = SMEM;
    short* Bs = SMEM + 128 * 64;

    int bx = blockIdx.x;
    int mt = bx & 127;
    int y = bx >> 7;
    int w = y >> 2, nt = y & 3;
    int m0 = mt * 128, n0 = nt * 128;

    int tid = threadIdx.x;
    int wid = tid >> 6, lane = tid & 63;
    int wr = wid >> 1, wc = wid & 1;
    int ln = lane & 15, hi = lane >> 4;

    f32x4 acc[4][4];
    for (int i = 0; i < 4; ++i) for (int j = 0; j < 4; ++j) acc[i][j] = {0.f, 0.f, 0.f, 0.f};

    const short* WtW = Wt + (size_t)w * 512 * 512;

    for (int ko = 0; ko < 8; ++ko) {
        int k0 = ko * 64;
        __syncthreads();
        for (int j = 0; j < 8; ++j) {
            int c = j * 256 + tid;
            int row = c >> 4, col4 = c & 15;
            float4 v = *reinterpret_cast<const float4*>(&X[(size_t)(m0 + row) * 512 + k0 + col4 * 4]);
            short4b s;
            s[0] = f2bf(v.x); s[1] = f2bf(v.y); s[2] = f2bf(v.z); s[3] = f2bf(v.w);
            *reinterpret_cast<short4b*>(&As[row * 64 + ((col4 * 4) ^ ((row & 7) << 3))]) = s;
        }
        for (int j = 0; j < 4; ++j) {
            int c = j * 256 + tid;
            int row = c >> 3, col8 = c & 7;
            short8 v = *reinterpret_cast<const short8*>(&WtW[(size_t)(n0 + row) * 512 + k0 + col8 * 8]);
            *reinterpret_cast<short8*>(&Bs[row * 64 + ((col8 * 8) ^ ((row & 7) << 3))]) = v;
        }
        __syncthreads();
        for (int kk = 0; kk < 2; ++kk) {
            int kof = kk * 32 + hi * 8;
            int sw = (ln & 7) << 3;
            short8 af[4], bf[4];
            for (int mf = 0; mf < 4; ++mf)
                af[mf] = *reinterpret_cast<const short8*>(&As[(wr * 64 + mf * 16 + ln) * 64 + (kof ^ sw)]);
            for (int nf = 0; nf < 4; ++nf)
                bf[nf] = *reinterpret_cast<const short8*>(&Bs[(wc * 64 + nf * 16 + ln) * 64 + (kof ^ sw)]);
            for (int mf = 0; mf < 4; ++mf)
                for (int nf = 0; nf < 4; ++nf)
                    acc[mf][nf] = __builtin_amdgcn_mfma_f32_16x16x32_bf16(af[mf], bf[nf], acc[mf][nf], 0, 0, 0);
        }
    }
    __syncthreads();

    if (w < 2) {
        short* O = (w == 0) ? Qb : Kb;
        for (int mf = 0; mf < 4; ++mf)
            for (int nf = 0; nf < 4; ++nf)
                for (int j = 0; j < 4; ++j) {
                    int row = m0 + wr * 64 + mf * 16 + hi * 4 + j;
                    int col = n0 + wc * 64 + nf * 16 + ln;
                    O[(size_t)row * 512 + col] = f2bf(sigm(acc[mf][nf][j]));
                }
    } else {
        for (int mf = 0; mf < 4; ++mf)
            for (int nf = 0; nf < 4; ++nf)
                for (int j = 0; j < 4; ++j) {
                    int ml = wr * 64 + mf * 16 + hi * 4 + j;       // s-local
                    int nl = wc * 64 + nf * 16 + ln;               // d-local
                    SMEM[nl * 128 + (ml ^ ((nl & 7) << 3))] = f2bf(sigm(acc[mf][nf][j]));
                }
        __syncthreads();
        int bb = m0 >> 11;
        int s0 = m0 & 2047;
        int d = tid >> 1, h = tid & 1;
        for (int i = 0; i < 8; ++i) {
            int s8 = h * 64 + i * 8;
            short8 v = *reinterpret_cast<const short8*>(&SMEM[d * 128 + (s8 ^ ((d & 7) << 3))]);
            *reinterpret_cast<short8*>(&VtG[((size_t)(bb * 512 + n0 + d)) * 2048 + s0 + s8]) = v;
        }
    }
}

// ---------------------------------------------------------------- PA: score pass
// 1088 blocks: b=bid&7 (XCD), idx=bid>>3 in [0,136) -> causal tile (ti,tj), ti>=tj.
// Computes 128x128 tile of P = exp(mask(Q K^T scale)) -> Pc (compact bf16),
// and per-row sums -> Dpart[b][tj][2048].
__global__ __launch_bounds__(256) void score_pass(
    const short* __restrict__ Qb, const short* __restrict__ Kb,
    short* __restrict__ Pc, float* __restrict__ Dpart)
{
    __shared__ short SMEM[128 * 128];       // As | Bs
    __shared__ float psum[2][128];
    short* As = SMEM;
    short* Bs = SMEM + 128 * 64;

    const float scale = 0.044194173824159216f;   // 1/sqrt(512)

    int bid = blockIdx.x;
    int b = bid & 7;
    int idx = bid >> 3;
    int ti = 0;
    while ((ti + 1) * (ti + 2) / 2 <= idx) ++ti;
    int tj = idx - ti * (ti + 1) / 2;
    int m0 = ti * 128, n0 = tj * 128;

    int tid = threadIdx.x;
    int w = tid >> 6, lane = tid & 63;
    int wr = w >> 1, wc = w & 1;
    int ln = lane & 15, hi = lane >> 4;

    const short* Qsrc = Qb + (size_t)b * 2048 * 512 + (size_t)m0 * 512;
    const short* Ksrc = Kb + (size_t)b * 2048 * 512 + (size_t)n0 * 512;

    f32x4 acc[4][4];
#pragma unroll
    for (int i = 0; i < 4; ++i)
#pragma unroll
        for (int j = 0; j < 4; ++j) acc[i][j] = {0.f, 0.f, 0.f, 0.f};

    for (int ko = 0; ko < 8; ++ko) {
        int k0 = ko * 64;
        // stage A (Q) and B (K): 128x64 bf16 each, gload_lds w/ pre-swizzled source
#pragma unroll
        for (int j = 0; j < 4; ++j) {
            int r = w * 8 + j * 32 + (lane >> 3);
            int sc = ((lane & 7) * 8) ^ ((r & 7) << 3);
            gload_lds16(Qsrc + (size_t)r * 512 + k0 + sc, &As[(w * 8 + j * 32) * 64]);
        }
#pragma unroll
        for (int j = 0; j < 4; ++j) {
            int r = w * 8 + j * 32 + (lane >> 3);
            int sc = ((lane & 7) * 8) ^ ((r & 7) << 3);
            gload_lds16(Ksrc + (size_t)r * 512 + k0 + sc, &Bs[(w * 8 + j * 32) * 64]);
        }
        __syncthreads();                     // drains vmcnt -> tiles visible
#pragma unroll
        for (int kk = 0; kk < 2; ++kk) {
            int kof = kk * 32 + hi * 8;
            int sw = (ln & 7) << 3;
            short8 af[4], bf[4];
#pragma unroll
            for (int mf = 0; mf < 4; ++mf)
                af[mf] = *reinterpret_cast<const short8*>(&As[(wr * 64 + mf * 16 + ln) * 64 + (kof ^ sw)]);
#pragma unroll
            for (int nf = 0; nf < 4; ++nf)
                bf[nf] = *reinterpret_cast<const short8*>(&Bs[(wc * 64 + nf * 16 + ln) * 64 + (kof ^ sw)]);
#pragma unroll
            for (int mf = 0; mf < 4; ++mf)
#pragma unroll
                for (int nf = 0; nf < 4; ++nf)
                    acc[mf][nf] = __builtin_amdgcn_mfma_f32_16x16x32_bf16(af[mf], bf[nf], acc[mf][nf], 0, 0, 0);
        }
        __syncthreads();
    }

    // epilogue: mask (strict j<i), exp, write P bf16, row-sum partials
    short* Ptile = Pc + (size_t)(b * 136 + idx) * 128 * 128;
#pragma unroll
    for (int mf = 0; mf < 4; ++mf) {
        float rs[4] = {0.f, 0.f, 0.f, 0.f};
#pragma unroll
        for (int nf = 0; nf < 4; ++nf)
#pragma unroll
            for (int j = 0; j < 4; ++j) {
                int rl = wr * 64 + mf * 16 + hi * 4 + j;
                int cl = wc * 64 + nf * 16 + ln;
                int irow = m0 + rl, jcol = n0 + cl;
                float p = (jcol < irow) ? __expf(acc[mf][nf][j] * scale) : 0.f;
                short hs = f2bf(p);
                Ptile[(size_t)rl * 128 + cl] = hs;
                rs[j] += bf2f(hs);
            }
#pragma unroll
        for (int j = 0; j < 4; ++j) {
            float s = rs[j];
            s += __shfl_xor(s, 1);
            s += __shfl_xor(s, 2);
            s += __shfl_xor(s, 4);
            s += __shfl_xor(s, 8);
            if (ln == 0) psum[wc][wr * 64 + mf * 16 + hi * 4 + j] = s;
        }
    }
    __syncthreads();
    if (tid < 128)
        Dpart[((size_t)b * 16 + tj) * 2048 + m0 + tid] = psum[0][tid] + psum[1][tid];
}

// ---------------------------------------------------------------- PB: PV pass
// 1024 blocks: b=bid&7, rr=bid>>3 in [0,128). Balanced decode: grp=rr>>5, off=rr&31;
// ti = (grp&1) ? 15-(off>>1) : off>>1 ; colhalf = 2*grp + (off&1) -> n0 = colhalf*64.
// O[128 rows][64 cols] = sum_{tj<=ti} P_tile(ti,tj) @ V^T-slice, scaled by 1/denom.
__global__ __launch_bounds__(256) void pv_pass(
    const short* __restrict__ Pc, const short* __restrict__ VtG,
    const float* __restrict__ Dpart, float* __restrict__ Out)
{
    __shared__ short SMEM[128 * 64 + 64 * 64];   // As (P) | Bs (V^T)
    __shared__ float dnm[128];
    short* As = SMEM;
    short* Bs = SMEM + 128 * 64;

    int bid = blockIdx.x;
    int b = bid & 7;
    int rr = bid >> 3;
    int grp = rr >> 5, off = rr & 31;
    int ti = (grp & 1) ? (15 - (off >> 1)) : (off >> 1);
    int colhalf = 2 * grp + (off & 1);
    int m0 = ti * 128, n0 = colhalf * 64;

    int tid = threadIdx.x;
    int w = tid >> 6, lane = tid & 63;
    int wr = w >> 1, wc = w & 1;
    int ln = lane & 15, hi = lane >> 4;

    // prologue: denominators for this row-block (visible by first __syncthreads)
    if (tid < 128) {
        float s = 0.f;
        for (int tj = 0; tj <= ti; ++tj)
            s += Dpart[((size_t)b * 16 + tj) * 2048 + m0 + tid];
        int gi = m0 + tid;
        dnm[tid] = (gi == 0) ? 0.f : 1.0f / s;
    }

    const short* Ptiles = Pc + (size_t)(b * 136 + ti * (ti + 1) / 2) * 128 * 128;
    const short* Vsrc = VtG + (size_t)b * 512 * 2048 + (size_t)n0 * 2048;

    f32x4 acc[4][2];
#pragma unroll
    for (int i = 0; i < 4; ++i)
#pragma unroll
        for (int j = 0; j < 2; ++j) acc[i][j] = {0.f, 0.f, 0.f, 0.f};

    for (int ks = 0; ks < 2 * (ti + 1); ++ks) {
        int tj = ks >> 1;
        int j0 = (ks & 1) * 64;                 // k-offset within the 128-wide tile
        const short* Pt = Ptiles + (size_t)tj * 128 * 128;
        // stage As: P[128 rows][64 k] (row stride 128 shorts)
#pragma unroll
        for (int j = 0; j < 4; ++j) {
            int r = w * 8 + j * 32 + (lane >> 3);
            int sc = ((lane & 7) * 8) ^ ((r & 7) << 3);
            gload_lds16(Pt + (size_t)r * 128 + j0 + sc, &As[(w * 8 + j * 32) * 64]);
        }
        // stage Bs: V^T[64 d][64 k] (row stride 2048 shorts), k = tj*128 + j0
#pragma unroll
        for (int j = 0; j < 2; ++j) {
            int r = w * 8 + j * 32 + (lane >> 3);
            int sc = ((lane & 7) * 8) ^ ((r & 7) << 3);
            gload_lds16(Vsrc + (size_t)r * 2048 + tj * 128 + j0 + sc, &Bs[(w * 8 + j * 32) * 64]);
        }
        __syncthreads();
#pragma unroll
        for (int kk = 0; kk < 2; ++kk) {
            int kof = kk * 32 + hi * 8;
            int sw = (ln & 7) << 3;
            short8 af[4], bf[2];
#pragma unroll
            for (int mf = 0; mf < 4; ++mf)
                af[mf] = *reinterpret_cast<const short8*>(&As[(wr * 64 + mf * 16 + ln) * 64 + (kof ^ sw)]);
#pragma unroll
            for (int nf = 0; nf < 2; ++nf)
                bf[nf] = *reinterpret_cast<const short8*>(&Bs[(wc * 32 + nf * 16 + ln) * 64 + (kof ^ sw)]);
#pragma unroll
            for (int mf = 0; mf < 4; ++mf)
#pragma unroll
                for (int nf = 0; nf < 2; ++nf)
                    acc[mf][nf] = __builtin_amdgcn_mfma_f32_16x16x32_bf16(af[mf], bf[nf], acc[mf][nf], 0, 0, 0);
        }
        __syncthreads();
    }

    // epilogue: scale by 1/denom, store fp32
#pragma unroll
    for (int mf = 0; mf < 4; ++mf)
#pragma unroll
        for (int j = 0; j < 4; ++j) {
            int rl = wr * 64 + mf * 16 + hi * 4 + j;
            float rd = dnm[rl];
            float* orow = Out + ((size_t)b * 2048 + m0 + rl) * 512 + n0 + wc * 32 + ln;
#pragma unroll
            for (int nf = 0; nf < 2; ++nf)
                orow[nf * 16] = acc[mf][nf][j] * rd;
        }
}

// ---------------------------------------------------------------- launch
extern "C" void kernel_launch(void* const* d_in, const int* in_sizes, int n_in,
                              void* d_out, int out_size, void* d_ws, size_t ws_size,
                              hipStream_t stream) {
    const float* X  = (const float*)d_in[0];
    const float* Wq = (const float*)d_in[1];
    const float* Wv = (const float*)d_in[2];
    const float* Wk = (const float*)d_in[3];
    float* Out = (float*)d_out;

    char* ws = (char*)d_ws;
    const size_t WT_BYTES  = (size_t)3 * 512 * 512 * 2;        // 1.5 MB
    const size_t MAT_BYTES = (size_t)16384 * 512 * 2;          // 16 MB each
    const size_t PC_BYTES  = (size_t)8 * 136 * 128 * 128 * 2;  // 34.9 MB
    short* Wt = (short*)ws;
    short* Qb = (short*)(ws + WT_BYTES);
    short* Kb = (short*)(ws + WT_BYTES + MAT_BYTES);
    short* Vt = (short*)(ws + WT_BYTES + 2 * MAT_BYTES);
    short* Pc = (short*)(ws + WT_BYTES + 3 * MAT_BYTES);
    float* Dp = (float*)(ws + WT_BYTES + 3 * MAT_BYTES + PC_BYTES);

    prep_weights<<<192, 256, 0, stream>>>(Wq, Wv, Wk, Wt);
    qkv_gemm<<<1536, 256, 0, stream>>>(X, Wt, Qb, Kb, Vt);
    score_pass<<<1088, 256, 0, stream>>>(Qb, Kb, Pc, Dp);
    pv_pass<<<1024, 256, 0, stream>>>(Pc, Vt, Dp, Out);
}

// Round 8
// 137.120 us; speedup vs baseline: 1.5314x; 1.0352x over previous
//
#include <hip/hip_runtime.h>
#include <stdint.h>

// Round 8: qkv_gemm de-VALU-ified.
//  - convert_x: X fp32 -> Xb bf16 once (memory-bound, ~8us). Xb aliases Pc region
//    (dead before score_pass writes Pc) -> zero extra ws.
//  - qkv_gemm: A and B staged via global_load_lds w/ pre-swizzled source (the exact
//    staging R7's score_pass validated). Epilogue unchanged. R7 profile: VALUBusy 31%
//    from in-loop fp32->bf16 converts + ds_writes; this removes all of it.
//  score_pass/pv_pass/prep unchanged (proven R7).

typedef __attribute__((ext_vector_type(4))) float f32x4;
typedef __attribute__((ext_vector_type(8))) short short8;
typedef __attribute__((ext_vector_type(4))) short short4b;

__device__ __forceinline__ short f2bf(float f) {
    union { float f; uint32_t u; } v; v.f = f;
    uint32_t r = (v.u + 0x7FFFu + ((v.u >> 16) & 1u)) >> 16;   // RNE
    return (short)r;
}
__device__ __forceinline__ float bf2f(short s) {
    union { uint32_t u; float f; } v; v.u = ((uint32_t)(uint16_t)s) << 16; return v.f;
}
__device__ __forceinline__ float sigm(float x) { return 1.0f / (1.0f + __expf(-x)); }

__device__ __forceinline__ void gload_lds16(const void* g, void* l) {
    __builtin_amdgcn_global_load_lds(
        (const __attribute__((address_space(1))) void*)g,
        (__attribute__((address_space(3))) void*)l, 16, 0, 0);
}

// ---------------------------------------------------------------- K0: X fp32 -> bf16
__global__ __launch_bounds__(256) void convert_x(
    const float* __restrict__ X, short* __restrict__ Xb)
{
    size_t i = (size_t)blockIdx.x * 256 + threadIdx.x;     // 8 floats/thread
    const float4* src = reinterpret_cast<const float4*>(X) + i * 2;
    float4 a = src[0], b = src[1];
    short8 o;
    o[0] = f2bf(a.x); o[1] = f2bf(a.y); o[2] = f2bf(a.z); o[3] = f2bf(a.w);
    o[4] = f2bf(b.x); o[5] = f2bf(b.y); o[6] = f2bf(b.z); o[7] = f2bf(b.w);
    *reinterpret_cast<short8*>(Xb + i * 8) = o;
}

// ---------------------------------------------------------------- K1: weights
__global__ __launch_bounds__(256) void prep_weights(
    const float* __restrict__ Wq, const float* __restrict__ Wv, const float* __restrict__ Wk,
    short* __restrict__ Wt)
{
    __shared__ float T[64 * 68];
    int bid = blockIdx.x;
    int w = bid >> 6;                 // 0..2
    int tile = bid & 63;
    int n0 = (tile & 7) * 64;
    int k0 = (tile >> 3) * 64;
    const float* W = (w == 0) ? Wq : (w == 1) ? Wv : Wk;
    int t = threadIdx.x;
    int tr = t >> 4, tc = t & 15;
    for (int rr = 0; rr < 4; ++rr) {
        int row = rr * 16 + tr;       // k-local
        float4 v = *reinterpret_cast<const float4*>(&W[(size_t)(k0 + row) * 512 + n0 + tc * 4]);
        T[row * 68 + tc * 4 + 0] = v.x;
        T[row * 68 + tc * 4 + 1] = v.y;
        T[row * 68 + tc * 4 + 2] = v.z;
        T[row * 68 + tc * 4 + 3] = v.w;
    }
    __syncthreads();
    for (int wr = 0; wr < 4; ++wr) {
        int nl = wr * 16 + tr;        // n-local
        short4b o;
        for (int i = 0; i < 4; ++i) o[i] = f2bf(T[(tc * 4 + i) * 68 + nl]);
        *reinterpret_cast<short4b*>(&Wt[((size_t)(w * 512 + n0 + nl)) * 512 + k0 + tc * 4]) = o;
    }
}

// ---------------------------------------------------------------- K2: QKV GEMM (bf16 in, gload_lds staging)
__global__ __launch_bounds__(256) void qkv_gemm(
    const short* __restrict__ Xb,    // [16384][512] bf16
    const short* __restrict__ Wt,    // [3][512 n][512 k] bf16
    short* __restrict__ Qb, short* __restrict__ Kb, short* __restrict__ VtG)
{
    __shared__ short SMEM[128 * 128];
    short* As = SMEM;
    short* Bs = SMEM + 128 * 64;

    int bx = blockIdx.x;
    int mt = bx & 127;
    int y = bx >> 7;
    int w = y >> 2, nt = y & 3;
    int m0 = mt * 128, n0 = nt * 128;

    int tid = threadIdx.x;
    int wv = tid >> 6, lane = tid & 63;
    int wr = wv >> 1, wc = wv & 1;
    int ln = lane & 15, hi = lane >> 4;

    f32x4 acc[4][4];
#pragma unroll
    for (int i = 0; i < 4; ++i)
#pragma unroll
        for (int j = 0; j < 4; ++j) acc[i][j] = {0.f, 0.f, 0.f, 0.f};

    const short* Asrc = Xb + (size_t)m0 * 512;
    const short* Bsrc = Wt + (size_t)w * 512 * 512 + (size_t)n0 * 512;

    for (int ko = 0; ko < 8; ++ko) {
        int k0 = ko * 64;
        // stage A (Xb) and B (Wt): 128x64 bf16 each, pre-swizzled source, linear dest
#pragma unroll
        for (int j = 0; j < 4; ++j) {
            int r = wv * 8 + j * 32 + (lane >> 3);
            int sc = ((lane & 7) * 8) ^ ((r & 7) << 3);
            gload_lds16(Asrc + (size_t)r * 512 + k0 + sc, &As[(wv * 8 + j * 32) * 64]);
        }
#pragma unroll
        for (int j = 0; j < 4; ++j) {
            int r = wv * 8 + j * 32 + (lane >> 3);
            int sc = ((lane & 7) * 8) ^ ((r & 7) << 3);
            gload_lds16(Bsrc + (size_t)r * 512 + k0 + sc, &Bs[(wv * 8 + j * 32) * 64]);
        }
        __syncthreads();                     // drains vmcnt -> tiles visible
#pragma unroll
        for (int kk = 0; kk < 2; ++kk) {
            int kof = kk * 32 + hi * 8;
            int sw = (ln & 7) << 3;
            short8 af[4], bf[4];
#pragma unroll
            for (int mf = 0; mf < 4; ++mf)
                af[mf] = *reinterpret_cast<const short8*>(&As[(wr * 64 + mf * 16 + ln) * 64 + (kof ^ sw)]);
#pragma unroll
            for (int nf = 0; nf < 4; ++nf)
                bf[nf] = *reinterpret_cast<const short8*>(&Bs[(wc * 64 + nf * 16 + ln) * 64 + (kof ^ sw)]);
#pragma unroll
            for (int mf = 0; mf < 4; ++mf)
#pragma unroll
                for (int nf = 0; nf < 4; ++nf)
                    acc[mf][nf] = __builtin_amdgcn_mfma_f32_16x16x32_bf16(af[mf], bf[nf], acc[mf][nf], 0, 0, 0);
        }
        __syncthreads();
    }

    if (w < 2) {
        short* O = (w == 0) ? Qb : Kb;
#pragma unroll
        for (int mf = 0; mf < 4; ++mf)
#pragma unroll
            for (int nf = 0; nf < 4; ++nf)
#pragma unroll
                for (int j = 0; j < 4; ++j) {
                    int row = m0 + wr * 64 + mf * 16 + hi * 4 + j;
                    int col = n0 + wc * 64 + nf * 16 + ln;
                    O[(size_t)row * 512 + col] = f2bf(sigm(acc[mf][nf][j]));
                }
    } else {
        // V: transpose via LDS, store Vt[b][d][s]
#pragma unroll
        for (int mf = 0; mf < 4; ++mf)
#pragma unroll
            for (int nf = 0; nf < 4; ++nf)
#pragma unroll
                for (int j = 0; j < 4; ++j) {
                    int ml = wr * 64 + mf * 16 + hi * 4 + j;       // s-local
                    int nl = wc * 64 + nf * 16 + ln;               // d-local
                    SMEM[nl * 128 + (ml ^ ((nl & 7) << 3))] = f2bf(sigm(acc[mf][nf][j]));
                }
        __syncthreads();
        int bb = m0 >> 11;
        int s0 = m0 & 2047;
        int d = tid >> 1, h = tid & 1;
#pragma unroll
        for (int i = 0; i < 8; ++i) {
            int s8 = h * 64 + i * 8;
            short8 v = *reinterpret_cast<const short8*>(&SMEM[d * 128 + (s8 ^ ((d & 7) << 3))]);
            *reinterpret_cast<short8*>(&VtG[((size_t)(bb * 512 + n0 + d)) * 2048 + s0 + s8]) = v;
        }
    }
}

// ---------------------------------------------------------------- PA: score pass
// 1088 blocks: b=bid&7 (XCD), idx=bid>>3 in [0,136) -> causal tile (ti,tj), ti>=tj.
__global__ __launch_bounds__(256) void score_pass(
    const short* __restrict__ Qb, const short* __restrict__ Kb,
    short* __restrict__ Pc, float* __restrict__ Dpart)
{
    __shared__ short SMEM[128 * 128];       // As | Bs
    __shared__ float psum[2][128];
    short* As = SMEM;
    short* Bs = SMEM + 128 * 64;

    const float scale = 0.044194173824159216f;   // 1/sqrt(512)

    int bid = blockIdx.x;
    int b = bid & 7;
    int idx = bid >> 3;
    int ti = 0;
    while ((ti + 1) * (ti + 2) / 2 <= idx) ++ti;
    int tj = idx - ti * (ti + 1) / 2;
    int m0 = ti * 128, n0 = tj * 128;

    int tid = threadIdx.x;
    int w = tid >> 6, lane = tid & 63;
    int wr = w >> 1, wc = w & 1;
    int ln = lane & 15, hi = lane >> 4;

    const short* Qsrc = Qb + (size_t)b * 2048 * 512 + (size_t)m0 * 512;
    const short* Ksrc = Kb + (size_t)b * 2048 * 512 + (size_t)n0 * 512;

    f32x4 acc[4][4];
#pragma unroll
    for (int i = 0; i < 4; ++i)
#pragma unroll
        for (int j = 0; j < 4; ++j) acc[i][j] = {0.f, 0.f, 0.f, 0.f};

    for (int ko = 0; ko < 8; ++ko) {
        int k0 = ko * 64;
#pragma unroll
        for (int j = 0; j < 4; ++j) {
            int r = w * 8 + j * 32 + (lane >> 3);
            int sc = ((lane & 7) * 8) ^ ((r & 7) << 3);
            gload_lds16(Qsrc + (size_t)r * 512 + k0 + sc, &As[(w * 8 + j * 32) * 64]);
        }
#pragma unroll
        for (int j = 0; j < 4; ++j) {
            int r = w * 8 + j * 32 + (lane >> 3);
            int sc = ((lane & 7) * 8) ^ ((r & 7) << 3);
            gload_lds16(Ksrc + (size_t)r * 512 + k0 + sc, &Bs[(w * 8 + j * 32) * 64]);
        }
        __syncthreads();
#pragma unroll
        for (int kk = 0; kk < 2; ++kk) {
            int kof = kk * 32 + hi * 8;
            int sw = (ln & 7) << 3;
            short8 af[4], bf[4];
#pragma unroll
            for (int mf = 0; mf < 4; ++mf)
                af[mf] = *reinterpret_cast<const short8*>(&As[(wr * 64 + mf * 16 + ln) * 64 + (kof ^ sw)]);
#pragma unroll
            for (int nf = 0; nf < 4; ++nf)
                bf[nf] = *reinterpret_cast<const short8*>(&Bs[(wc * 64 + nf * 16 + ln) * 64 + (kof ^ sw)]);
#pragma unroll
            for (int mf = 0; mf < 4; ++mf)
#pragma unroll
                for (int nf = 0; nf < 4; ++nf)
                    acc[mf][nf] = __builtin_amdgcn_mfma_f32_16x16x32_bf16(af[mf], bf[nf], acc[mf][nf], 0, 0, 0);
        }
        __syncthreads();
    }

    // epilogue: mask (strict j<i), exp, write P bf16, row-sum partials
    short* Ptile = Pc + (size_t)(b * 136 + idx) * 128 * 128;
#pragma unroll
    for (int mf = 0; mf < 4; ++mf) {
        float rs[4] = {0.f, 0.f, 0.f, 0.f};
#pragma unroll
        for (int nf = 0; nf < 4; ++nf)
#pragma unroll
            for (int j = 0; j < 4; ++j) {
                int rl = wr * 64 + mf * 16 + hi * 4 + j;
                int cl = wc * 64 + nf * 16 + ln;
                int irow = m0 + rl, jcol = n0 + cl;
                float p = (jcol < irow) ? __expf(acc[mf][nf][j] * scale) : 0.f;
                short hs = f2bf(p);
                Ptile[(size_t)rl * 128 + cl] = hs;
                rs[j] += bf2f(hs);
            }
#pragma unroll
        for (int j = 0; j < 4; ++j) {
            float s = rs[j];
            s += __shfl_xor(s, 1);
            s += __shfl_xor(s, 2);
            s += __shfl_xor(s, 4);
            s += __shfl_xor(s, 8);
            if (ln == 0) psum[wc][wr * 64 + mf * 16 + hi * 4 + j] = s;
        }
    }
    __syncthreads();
    if (tid < 128)
        Dpart[((size_t)b * 16 + tj) * 2048 + m0 + tid] = psum[0][tid] + psum[1][tid];
}

// ---------------------------------------------------------------- PB: PV pass
__global__ __launch_bounds__(256) void pv_pass(
    const short* __restrict__ Pc, const short* __restrict__ VtG,
    const float* __restrict__ Dpart, float* __restrict__ Out)
{
    __shared__ short SMEM[128 * 64 + 64 * 64];   // As (P) | Bs (V^T)
    __shared__ float dnm[128];
    short* As = SMEM;
    short* Bs = SMEM + 128 * 64;

    int bid = blockIdx.x;
    int b = bid & 7;
    int rr = bid >> 3;
    int grp = rr >> 5, off = rr & 31;
    int ti = (grp & 1) ? (15 - (off >> 1)) : (off >> 1);
    int colhalf = 2 * grp + (off & 1);
    int m0 = ti * 128, n0 = colhalf * 64;

    int tid = threadIdx.x;
    int w = tid >> 6, lane = tid & 63;
    int wr = w >> 1, wc = w & 1;
    int ln = lane & 15, hi = lane >> 4;

    if (tid < 128) {
        float s = 0.f;
        for (int tj = 0; tj <= ti; ++tj)
            s += Dpart[((size_t)b * 16 + tj) * 2048 + m0 + tid];
        int gi = m0 + tid;
        dnm[tid] = (gi == 0) ? 0.f : 1.0f / s;
    }

    const short* Ptiles = Pc + (size_t)(b * 136 + ti * (ti + 1) / 2) * 128 * 128;
    const short* Vsrc = VtG + (size_t)b * 512 * 2048 + (size_t)n0 * 2048;

    f32x4 acc[4][2];
#pragma unroll
    for (int i = 0; i < 4; ++i)
#pragma unroll
        for (int j = 0; j < 2; ++j) acc[i][j] = {0.f, 0.f, 0.f, 0.f};

    for (int ks = 0; ks < 2 * (ti + 1); ++ks) {
        int tj = ks >> 1;
        int j0 = (ks & 1) * 64;
        const short* Pt = Ptiles + (size_t)tj * 128 * 128;
#pragma unroll
        for (int j = 0; j < 4; ++j) {
            int r = w * 8 + j * 32 + (lane >> 3);
            int sc = ((lane & 7) * 8) ^ ((r & 7) << 3);
            gload_lds16(Pt + (size_t)r * 128 + j0 + sc, &As[(w * 8 + j * 32) * 64]);
        }
#pragma unroll
        for (int j = 0; j < 2; ++j) {
            int r = w * 8 + j * 32 + (lane >> 3);
            int sc = ((lane & 7) * 8) ^ ((r & 7) << 3);
            gload_lds16(Vsrc + (size_t)r * 2048 + tj * 128 + j0 + sc, &Bs[(w * 8 + j * 32) * 64]);
        }
        __syncthreads();
#pragma unroll
        for (int kk = 0; kk < 2; ++kk) {
            int kof = kk * 32 + hi * 8;
            int sw = (ln & 7) << 3;
            short8 af[4], bf[2];
#pragma unroll
            for (int mf = 0; mf < 4; ++mf)
                af[mf] = *reinterpret_cast<const short8*>(&As[(wr * 64 + mf * 16 + ln) * 64 + (kof ^ sw)]);
#pragma unroll
            for (int nf = 0; nf < 2; ++nf)
                bf[nf] = *reinterpret_cast<const short8*>(&Bs[(wc * 32 + nf * 16 + ln) * 64 + (kof ^ sw)]);
#pragma unroll
            for (int mf = 0; mf < 4; ++mf)
#pragma unroll
                for (int nf = 0; nf < 2; ++nf)
                    acc[mf][nf] = __builtin_amdgcn_mfma_f32_16x16x32_bf16(af[mf], bf[nf], acc[mf][nf], 0, 0, 0);
        }
        __syncthreads();
    }

#pragma unroll
    for (int mf = 0; mf < 4; ++mf)
#pragma unroll
        for (int j = 0; j < 4; ++j) {
            int rl = wr * 64 + mf * 16 + hi * 4 + j;
            float rd = dnm[rl];
            float* orow = Out + ((size_t)b * 2048 + m0 + rl) * 512 + n0 + wc * 32 + ln;
#pragma unroll
            for (int nf = 0; nf < 2; ++nf)
                orow[nf * 16] = acc[mf][nf][j] * rd;
        }
}

// ---------------------------------------------------------------- launch
extern "C" void kernel_launch(void* const* d_in, const int* in_sizes, int n_in,
                              void* d_out, int out_size, void* d_ws, size_t ws_size,
                              hipStream_t stream) {
    const float* X  = (const float*)d_in[0];
    const float* Wq = (const float*)d_in[1];
    const float* Wv = (const float*)d_in[2];
    const float* Wk = (const float*)d_in[3];
    float* Out = (float*)d_out;

    char* ws = (char*)d_ws;
    const size_t WT_BYTES  = (size_t)3 * 512 * 512 * 2;        // 1.5 MB
    const size_t MAT_BYTES = (size_t)16384 * 512 * 2;          // 16 MB each
    const size_t PC_BYTES  = (size_t)8 * 136 * 128 * 128 * 2;  // 34.9 MB
    short* Wt = (short*)ws;
    short* Qb = (short*)(ws + WT_BYTES);
    short* Kb = (short*)(ws + WT_BYTES + MAT_BYTES);
    short* Vt = (short*)(ws + WT_BYTES + 2 * MAT_BYTES);
    short* Pc = (short*)(ws + WT_BYTES + 3 * MAT_BYTES);
    short* Xb = Pc;                       // alias: Xb dead before score_pass writes Pc
    float* Dp = (float*)(ws + WT_BYTES + 3 * MAT_BYTES + PC_BYTES);

    convert_x<<<4096, 256, 0, stream>>>(X, Xb);
    prep_weights<<<192, 256, 0, stream>>>(Wq, Wv, Wk, Wt);
    qkv_gemm<<<1536, 256, 0, stream>>>(Xb, Wt, Qb, Kb, Vt);
    score_pass<<<1088, 256, 0, stream>>>(Qb, Kb, Pc, Dp);
    pv_pass<<<1024, 256, 0, stream>>>(Pc, Vt, Dp, Out);
}